// Round 4
// baseline (84027.936 us; speedup 1.0000x reference)
//
#include <hip/hip_runtime.h>
#include <hip/hip_bf16.h>

typedef __attribute__((ext_vector_type(4))) float f32x4;
typedef __attribute__((ext_vector_type(8))) short s16x8;
typedef __attribute__((ext_vector_type(4))) short s16x4;
typedef __attribute__((ext_vector_type(8))) unsigned short u16x8;
typedef __attribute__((ext_vector_type(4))) unsigned short u16x4;
typedef __attribute__((ext_vector_type(4))) float fv4;

#define DEV static __device__ __forceinline__

DEV unsigned short f2bf(float f) {
  union { float f; unsigned u; } v; v.f = f;
  return (unsigned short)((v.u + 0x7fffu + ((v.u >> 16) & 1u)) >> 16);
}
DEV float bf2f(unsigned short u) {
  union { unsigned u; float f; } v; v.u = ((unsigned)u) << 16; return v.f;
}

typedef const __attribute__((address_space(1))) void* gas_t;
typedef __attribute__((address_space(3))) void* las_t;
DEV void load_lds16(const void* g, void* l) {
  __builtin_amdgcn_global_load_lds((gas_t)g, (las_t)l, 16, 0, 0);
}

// ---------------- fp32 -> bf16 convert ----------------
__global__ __launch_bounds__(256) void cvt_kernel(const float* __restrict__ in,
                                                  unsigned short* __restrict__ out,
                                                  int n4) {
  int i = blockIdx.x * 256 + threadIdx.x;
  int stride = gridDim.x * 256;
  for (; i < n4; i += stride) {
    fv4 v = *(const fv4*)(in + (size_t)i * 4);
    u16x4 o;
    o[0] = f2bf(v[0]); o[1] = f2bf(v[1]); o[2] = f2bf(v[2]); o[3] = f2bf(v[3]);
    *(u16x4*)(out + (size_t)i * 4) = o;
  }
}

// ------- 256x256 BT GEMM, BK=32, ring-4 LDS, frag-pipelined phases ---------
// C[m,n] = sum_k A[m,k]*B[n,k].  M,N mult of 256, K mult of 128.
// Two phases per K-tile (m-quadrants). Each phase ISSUES next-phase ds_reads
// before its MFMA cluster; compiler's counted lgkmcnt leaves them in flight
// under the MFMA -> LDS pipe and matrix pipe overlap (the R2/R3 structures
// serialized them: wall = LDS + MFMA = 45% util; overlapped -> ~60%).
// Ring-4 staging (tile kt stages kt+3), counted vmcnt(6) gate once per tile.
// Swizzle (T2, verified R2: conflicts=0): byte ^= ((row>>1)&3)<<4 both sides.
// EPI: 0 = bf16 out (ldc=N), 1 = +bias[n] bf16, 2 = Vt mapping
//   addr = (n>>9)*2^21 + m*512 + (n&511)
template<int EPI>
__global__ __launch_bounds__(512, 1) void gemm256(const unsigned short* __restrict__ A,
                                                  const unsigned short* __restrict__ B,
                                                  unsigned short* __restrict__ C,
                                                  const float* __restrict__ bias,
                                                  int N, int K, int nbx_sh) {
  __shared__ unsigned short lds[4][2][8192]; // [slot][A/B][256*32] = 128 KiB
  const int t = threadIdx.x;
  const int lane = t & 63;
  const int w = t >> 6;
  const int wr = w >> 2;   // 0..1
  const int wc = w & 3;    // 0..3
  const int r0 = lane & 15;
  const int g = lane >> 4; // 0..3

  // T1: bijective XCD swizzle (gridDim.x % 8 == 0)
  const int nwg = gridDim.x;
  const int swz = (blockIdx.x & 7) * (nwg >> 3) + (blockIdx.x >> 3);
  const int by = swz >> nbx_sh;
  const int bx = swz & ((1 << nbx_sh) - 1);
  const long brow = (long)by * 256;
  const long bcol = (long)bx * 256;

  // staging: thread t -> 16B at LDS linear [t*8] and [4096+t*8]
  // dest row = t>>2 (0..127), chunk t&3; source chunk pre-swizzled by (t>>3)&3
  const int srow = t >> 2;
  const int scol = ((t & 3) ^ ((t >> 3) & 3)) * 8;
  const unsigned short* As = A + (brow + srow) * (long)K + scol;
  const unsigned short* Bs = B + (bcol + srow) * (long)K + scol;
  const int dst = t * 8;

#define STGA(slot, kt)                                                   \
  do {                                                                   \
    const long c0_ = (long)(kt) << 5;                                    \
    load_lds16(As + c0_,                 &lds[slot][0][dst]);            \
    load_lds16(As + 128 * (long)K + c0_, &lds[slot][0][4096 + dst]);     \
  } while (0)
#define STGB(slot, kt)                                                   \
  do {                                                                   \
    const long c0_ = (long)(kt) << 5;                                    \
    load_lds16(Bs + c0_,                 &lds[slot][1][dst]);            \
    load_lds16(Bs + 128 * (long)K + c0_, &lds[slot][1][4096 + dst]);     \
  } while (0)

  f32x4 acc[8][4] = {};
  const int NT = K >> 5;

  // swizzled k-chunk: (row>>1)&3 == (r0>>1)&3 for all frag rows
  const int cswz = (g ^ ((r0 >> 1) & 3)) * 8;
  const int arow = wr * 128 + r0;
  const int brw = wc * 64 + r0;

#define RD_A(Arr, slot, mq)                                                        \
  do {                                                                             \
    _Pragma("unroll")                                                              \
    for (int m = 0; m < 4; ++m)                                                    \
      Arr[m] = *(const s16x8*)&lds[slot][0][(arow + (mq) * 64 + m * 16) * 32 + cswz]; \
  } while (0)
#define RD_B(pp, slot)                                                             \
  do {                                                                             \
    _Pragma("unroll")                                                              \
    for (int n = 0; n < 4; ++n)                                                    \
      BF[pp][n] = *(const s16x8*)&lds[slot][1][(brw + n * 16) * 32 + cswz];        \
  } while (0)
#define MM(mq, Arr, pp)                                                            \
  do {                                                                             \
    _Pragma("unroll")                                                              \
    for (int m = 0; m < 4; ++m) {                                                  \
      _Pragma("unroll")                                                            \
      for (int n = 0; n < 4; ++n)                                                  \
        acc[(mq) * 4 + m][n] = __builtin_amdgcn_mfma_f32_16x16x32_bf16(            \
            Arr[m], BF[pp][n], acc[(mq) * 4 + m][n], 0, 0, 0);                     \
    }                                                                              \
  } while (0)

  s16x8 AF0[4], AF1[4];
  s16x8 BF[2][4];

  // prologue: stage tiles 0,1,2 (12 loads); drain tile 0 (leave 8); preload frags
  STGA(0, 0); STGB(0, 0);
  STGA(1, 1); STGB(1, 1);
  STGA(2, 2); STGB(2, 2);
  asm volatile("s_waitcnt vmcnt(8)" ::: "memory");
  __builtin_amdgcn_s_barrier();
  RD_A(AF0, 0, 0);
  RD_B(0, 0);

#pragma unroll 4
  for (int kt = 0; kt < NT; ++kt) {
    const int cb = kt & 3;
    const int pp = kt & 1;
    // ---- P0: MFMA quadrant m0-3 ; prefetch AF1 ; stage A(kt+3) ----
    if (kt + 3 < NT) STGA((kt + 3) & 3, kt + 3);
    RD_A(AF1, cb, 1);
    __builtin_amdgcn_sched_barrier(0);
    __builtin_amdgcn_s_setprio(1);
    MM(0, AF0, pp);
    __builtin_amdgcn_s_setprio(0);
    __builtin_amdgcn_sched_barrier(0);
    // gate: tile kt+1 fully in LDS (collective after barrier)
    if (kt < NT - 3)       asm volatile("s_waitcnt vmcnt(6)" ::: "memory");
    else if (kt == NT - 3) asm volatile("s_waitcnt vmcnt(4)" ::: "memory");
    else if (kt == NT - 2) asm volatile("s_waitcnt vmcnt(0)" ::: "memory");
    __builtin_amdgcn_s_barrier();
    __builtin_amdgcn_sched_barrier(0);
    // ---- P1: MFMA quadrant m4-7 ; prefetch next tile AF0/BF ; stage B(kt+3) ----
    if (kt + 3 < NT) STGB((kt + 3) & 3, kt + 3);
    if (kt + 1 < NT) {
      RD_A(AF0, (kt + 1) & 3, 0);
      RD_B(pp ^ 1, (kt + 1) & 3);
    }
    __builtin_amdgcn_sched_barrier(0);
    __builtin_amdgcn_s_setprio(1);
    MM(1, AF1, pp);
    __builtin_amdgcn_s_setprio(0);
    __builtin_amdgcn_sched_barrier(0);
    __builtin_amdgcn_s_barrier();
    __builtin_amdgcn_sched_barrier(0);
  }
#undef MM
#undef RD_B
#undef RD_A
#undef STGB
#undef STGA

  const int g4 = g * 4;
#pragma unroll
  for (int m = 0; m < 8; ++m) {
#pragma unroll
    for (int n = 0; n < 4; ++n) {
      f32x4 v = acc[m][n];
      long col = bcol + wc * 64 + n * 16 + r0;
#pragma unroll
      for (int r = 0; r < 4; ++r) {
        long row = brow + wr * 128 + m * 16 + g4 + r;
        float val = v[r];
        if (EPI == 1) val += bias[col];
        if (EPI == 2) {
          long addr = ((col >> 9) << 21) + (row << 9) + (col & 511);
          C[addr] = f2bf(val);
        } else {
          C[row * (long)N + col] = f2bf(val);
        }
      }
    }
  }
}

// ---------------- fused attention ----------------
// grid: 1024 = B(16) * NH(16) * 4 q-tiles ; block: 512 (8 waves x 16 q-rows)
__global__ __launch_bounds__(512, 2) void attn_kernel(const unsigned short* __restrict__ Q,
                                                      const unsigned short* __restrict__ K,
                                                      const unsigned short* __restrict__ V,
                                                      const unsigned short* __restrict__ EP,
                                                      float* __restrict__ out) {
  __shared__ unsigned short lds[256 * 136]; // also used as [128][264]
  const int t = threadIdx.x;
  const int lane = t & 63;
  const int w = t >> 6;
  const int bid = blockIdx.x;
  const int qt = bid & 3;
  const int h = (bid >> 2) & 15;
  const int b = bid >> 6;
  const int r0 = lane & 15;
  const int g = lane >> 4;

  const int qrow = qt * 128 + w * 16;

  s16x8 qf[8];
  {
    const unsigned short* qp = Q + ((size_t)(b * 512 + qrow + r0)) * 4096 + h * 256 + g * 8;
#pragma unroll
    for (int s = 0; s < 8; ++s) qf[s] = *(const s16x8*)(qp + s * 32);
  }

  f32x4 st[32];
#pragma unroll
  for (int f = 0; f < 32; ++f) st[f] = f32x4{0.f, 0.f, 0.f, 0.f};

#pragma unroll
  for (int kc = 0; kc < 4; ++kc) {
    {
      const unsigned short* kp = K + ((size_t)(b * 512 + kc * 128)) * 4096 + h * 256;
#pragma unroll
      for (int u = 0; u < 8; ++u) {
        int fidx = u * 4096 + t * 8;
        int row = fidx >> 8, c = fidx & 255;
        u16x8 v = *(const u16x8*)(kp + (size_t)row * 4096 + c);
        *(u16x8*)&lds[row * 264 + c] = v;
      }
    }
    __syncthreads();
#pragma unroll
    for (int mf = 0; mf < 8; ++mf) {
      const unsigned short* lk = &lds[(mf * 16 + r0) * 264 + g * 8];
#pragma unroll
      for (int s = 0; s < 8; ++s) {
        s16x8 af = *(const s16x8*)(lk + s * 32);
        st[kc * 8 + mf] = __builtin_amdgcn_mfma_f32_16x16x32_bf16(af, qf[s], st[kc * 8 + mf], 0, 0, 0);
      }
    }
    __syncthreads();
  }

  {
    const unsigned short* ep = EP + ((size_t)(b * 512 + qrow + r0)) * 8192 + h * 512 + g * 4;
#pragma unroll
    for (int f = 0; f < 32; ++f) {
      u16x4 e = *(const u16x4*)(ep + f * 16);
#pragma unroll
      for (int r = 0; r < 4; ++r)
        st[f][r] = st[f][r] * 0.0625f + bf2f(e[r]);
    }
  }

  float mx = -1e30f;
#pragma unroll
  for (int f = 0; f < 32; ++f)
    mx = fmaxf(mx, fmaxf(fmaxf(st[f][0], st[f][1]), fmaxf(st[f][2], st[f][3])));
  mx = fmaxf(mx, __shfl_xor(mx, 16, 64));
  mx = fmaxf(mx, __shfl_xor(mx, 32, 64));
  float sum = 0.f;
#pragma unroll
  for (int f = 0; f < 32; ++f) {
#pragma unroll
    for (int r = 0; r < 4; ++r) {
      float e = __expf(st[f][r] - mx);
      st[f][r] = e;
      sum += e;
    }
  }
  sum += __shfl_xor(sum, 16, 64);
  sum += __shfl_xor(sum, 32, 64);
  const float rinv = 1.0f / sum;

  s16x8 pb[16];
#pragma unroll
  for (int p = 0; p < 16; ++p) {
    s16x8 v;
#pragma unroll
    for (int j = 0; j < 4; ++j) {
      v[j] = (short)f2bf(st[2 * p][j] * rinv);
      v[j + 4] = (short)f2bf(st[2 * p + 1][j] * rinv);
    }
    pb[p] = v;
  }

  f32x4 acc2[16];
#pragma unroll
  for (int d = 0; d < 16; ++d) acc2[d] = f32x4{0.f, 0.f, 0.f, 0.f};

#pragma unroll
  for (int kc = 0; kc < 4; ++kc) {
    {
      const unsigned short* vp = V + ((size_t)(b * 16 + h)) * 131072 + kc * 128;
#pragma unroll
      for (int u = 0; u < 8; ++u) {
        int fidx = u * 4096 + t * 8;
        int row = fidx >> 7, c = fidx & 127;
        u16x8 vv = *(const u16x8*)(vp + (size_t)row * 512 + c);
        *(u16x8*)&lds[row * 136 + c] = vv;
      }
    }
    __syncthreads();
#pragma unroll
    for (int d = 0; d < 16; ++d) {
      const unsigned short* lv = &lds[(d * 16 + r0) * 136 + g * 4];
#pragma unroll
      for (int p = 0; p < 4; ++p) {
        s16x4 a0 = *(const s16x4*)(lv + p * 32);
        s16x4 a1 = *(const s16x4*)(lv + p * 32 + 16);
        s16x8 av;
        av[0] = a0[0]; av[1] = a0[1]; av[2] = a0[2]; av[3] = a0[3];
        av[4] = a1[0]; av[5] = a1[1]; av[6] = a1[2]; av[7] = a1[3];
        acc2[d] = __builtin_amdgcn_mfma_f32_16x16x32_bf16(av, pb[kc * 4 + p], acc2[d], 0, 0, 0);
      }
    }
    __syncthreads();
  }

  {
    float* op = out + ((size_t)(b * 512 + qrow + r0)) * 4096 + h * 256 + g * 4;
#pragma unroll
    for (int d = 0; d < 16; ++d)
      *(fv4*)(op + d * 16) = acc2[d];
  }
}

// ---------------- host launch ----------------
extern "C" void kernel_launch(void* const* d_in, const int* in_sizes, int n_in,
                              void* d_out, int out_size, void* d_ws, size_t ws_size,
                              hipStream_t stream) {
  const float* x   = (const float*)d_in[0];
  const float* aug = (const float*)d_in[1];
  const float* wq  = (const float*)d_in[2];
  const float* wk  = (const float*)d_in[3];
  const float* wv  = (const float*)d_in[4];
  const float* wp  = (const float*)d_in[5];
  const float* bp  = (const float*)d_in[6];
  float* out = (float*)d_out;

  const size_t OFF_XA = 0;                       // 64 MiB: x_bf, later aug_bf
  const size_t OFF_WQ = 67108864;                // 32 MiB
  const size_t OFF_WK = OFF_WQ + 33554432;       // 32 MiB
  const size_t OFF_WV = OFF_WK + 33554432;       // 32 MiB (wp_bf overlays WQ+WK)
  const size_t OFF_Q  = OFF_WQ + 100663296;      // 64 MiB
  const size_t OFF_K  = OFF_Q + 67108864;        // 64 MiB
  const size_t OFF_VT = OFF_K + 67108864;        // 64 MiB
  const size_t OFF_EP = OFF_VT + 67108864;       // 128 MiB
  const size_t NEED   = OFF_EP + 134217728;      // 480 MiB total
  if (ws_size < NEED) return;

  char* ws = (char*)d_ws;
  unsigned short* x_bf   = (unsigned short*)(ws + OFF_XA);
  unsigned short* aug_bf = (unsigned short*)(ws + OFF_XA);
  unsigned short* wq_bf  = (unsigned short*)(ws + OFF_WQ);
  unsigned short* wk_bf  = (unsigned short*)(ws + OFF_WK);
  unsigned short* wv_bf  = (unsigned short*)(ws + OFF_WV);
  unsigned short* wp_bf  = (unsigned short*)(ws + OFF_WQ);
  unsigned short* q_bf   = (unsigned short*)(ws + OFF_Q);
  unsigned short* k_bf   = (unsigned short*)(ws + OFF_K);
  unsigned short* vt_bf  = (unsigned short*)(ws + OFF_VT);
  unsigned short* ep_bf  = (unsigned short*)(ws + OFF_EP);

  // phase A: convert x + QKV weights
  cvt_kernel<<<2048, 256, 0, stream>>>(x, x_bf, 33554432 / 4);
  cvt_kernel<<<2048, 256, 0, stream>>>(wq, wq_bf, 16777216 / 4);
  cvt_kernel<<<2048, 256, 0, stream>>>(wk, wk_bf, 16777216 / 4);
  cvt_kernel<<<2048, 256, 0, stream>>>(wv, wv_bf, 16777216 / 4);

  // Q = x @ Wq^T ; K = x @ Wk^T   (M=8192, N=4096) grid 32x16=512
  gemm256<0><<<512, 512, 0, stream>>>(x_bf, wq_bf, q_bf, nullptr, 4096, 4096, 4);
  gemm256<0><<<512, 512, 0, stream>>>(x_bf, wk_bf, k_bf, nullptr, 4096, 4096, 4);
  // Vt = Wv @ x^T  (M=4096, N=8192) grid 16x32=512
  gemm256<2><<<512, 512, 0, stream>>>(wv_bf, x_bf, vt_bf, nullptr, 8192, 4096, 5);

  // phase B: x_bf dead -> reuse for aug; wq/wk dead -> reuse for wp
  cvt_kernel<<<2048, 256, 0, stream>>>(aug, aug_bf, 33554432 / 4);
  cvt_kernel<<<2048, 256, 0, stream>>>(wp, wp_bf, 33554432 / 4);
  // EP = Aug @ Wp^T + bp  (M=8192, N=8192) grid 32x32=1024
  gemm256<1><<<1024, 512, 0, stream>>>(aug_bf, wp_bf, ep_bf, bp, 8192, 4096, 5);

  // fused attention
  attn_kernel<<<1024, 512, 0, stream>>>(q_bf, k_bf, vt_bf, ep_bf, out);
}

// Round 5
// 1759.691 us; speedup vs baseline: 47.7515x; 47.7515x over previous
//
#include <hip/hip_runtime.h>
#include <hip/hip_bf16.h>

typedef __attribute__((ext_vector_type(4))) float f32x4;
typedef __attribute__((ext_vector_type(8))) short s16x8;
typedef __attribute__((ext_vector_type(4))) short s16x4;
typedef __attribute__((ext_vector_type(8))) unsigned short u16x8;
typedef __attribute__((ext_vector_type(4))) unsigned short u16x4;
typedef __attribute__((ext_vector_type(4))) float fv4;

#define DEV static __device__ __forceinline__

DEV unsigned short f2bf(float f) {
  union { float f; unsigned u; } v; v.f = f;
  return (unsigned short)((v.u + 0x7fffu + ((v.u >> 16) & 1u)) >> 16);
}
DEV float bf2f(unsigned short u) {
  union { unsigned u; float f; } v; v.u = ((unsigned)u) << 16; return v.f;
}

typedef const __attribute__((address_space(1))) void* gas_t;
typedef __attribute__((address_space(3))) void* las_t;
DEV void load_lds16(const void* g, void* l) {
  __builtin_amdgcn_global_load_lds((gas_t)g, (las_t)l, 16, 0, 0);
}

// ---------------- fp32 -> bf16 convert ----------------
__global__ __launch_bounds__(256) void cvt_kernel(const float* __restrict__ in,
                                                  unsigned short* __restrict__ out,
                                                  int n4) {
  int i = blockIdx.x * 256 + threadIdx.x;
  int stride = gridDim.x * 256;
  for (; i < n4; i += stride) {
    fv4 v = *(const fv4*)(in + (size_t)i * 4);
    u16x4 o;
    o[0] = f2bf(v[0]); o[1] = f2bf(v[1]); o[2] = f2bf(v[2]); o[3] = f2bf(v[3]);
    *(u16x4*)(out + (size_t)i * 4) = o;
  }
}

// ------- 256x256 BT GEMM, BK=32, ring-4 LDS, frag-pipelined phases ---------
// C[m,n] = sum_k A[m,k]*B[n,k].  M,N mult of 256, K mult of 128 (NT even).
// 2 K-tiles per loop iteration, 4 phases; ALL register arrays statically
// indexed (R4 lesson: runtime-indexed reg arrays -> scratch, 50x slowdown).
// Each phase issues next-phase ds_reads BEFORE its MFMA cluster so the
// compiler's counted lgkmcnt leaves them in flight under the MFMA (LDS pipe
// overlaps matrix pipe; R2/R3 serialized them at 45% util).
// Ring-4 staging at distance 3; counted vmcnt gates (6 steady; 4/0 tail).
// Swizzle (T2, verified: conflicts=0): byte ^= ((row>>1)&3)<<4 both sides.
// EPI: 0 = bf16 out (ldc=N), 1 = +bias[n] bf16, 2 = Vt mapping
//   addr = (n>>9)*2^21 + m*512 + (n&511)
template<int EPI>
__global__ __launch_bounds__(512, 2) void gemm256(const unsigned short* __restrict__ A,
                                                  const unsigned short* __restrict__ B,
                                                  unsigned short* __restrict__ C,
                                                  const float* __restrict__ bias,
                                                  int N, int K, int nbx_sh) {
  __shared__ unsigned short lds[4][2][8192]; // [slot][A/B][256*32] = 128 KiB
  const int t = threadIdx.x;
  const int lane = t & 63;
  const int w = t >> 6;
  const int wr = w >> 2;   // 0..1
  const int wc = w & 3;    // 0..3
  const int r0 = lane & 15;
  const int g = lane >> 4; // 0..3

  // T1: bijective XCD swizzle (gridDim.x % 8 == 0)
  const int nwg = gridDim.x;
  const int swz = (blockIdx.x & 7) * (nwg >> 3) + (blockIdx.x >> 3);
  const int by = swz >> nbx_sh;
  const int bx = swz & ((1 << nbx_sh) - 1);
  const long brow = (long)by * 256;
  const long bcol = (long)bx * 256;

  // staging: thread t -> 16B at LDS linear [t*8] and [4096+t*8]
  // dest row = t>>2 (0..127), chunk t&3; source chunk pre-swizzled by (t>>3)&3
  const int srow = t >> 2;
  const int scol = ((t & 3) ^ ((t >> 3) & 3)) * 8;
  const unsigned short* As = A + (brow + srow) * (long)K + scol;
  const unsigned short* Bs = B + (bcol + srow) * (long)K + scol;
  const int dst = t * 8;

#define STGA(slot, kt)                                                   \
  do {                                                                   \
    const long c0_ = (long)(kt) << 5;                                    \
    load_lds16(As + c0_,                 &lds[slot][0][dst]);            \
    load_lds16(As + 128 * (long)K + c0_, &lds[slot][0][4096 + dst]);     \
  } while (0)
#define STGB(slot, kt)                                                   \
  do {                                                                   \
    const long c0_ = (long)(kt) << 5;                                    \
    load_lds16(Bs + c0_,                 &lds[slot][1][dst]);            \
    load_lds16(Bs + 128 * (long)K + c0_, &lds[slot][1][4096 + dst]);     \
  } while (0)

  f32x4 acc[8][4] = {};
  const int NT = K >> 5; // even (K mult of 64; here 128)

  // swizzled k-chunk: (row>>1)&3 == (r0>>1)&3 for all frag rows
  const int cswz = (g ^ ((r0 >> 1) & 3)) * 8;
  const int arow = wr * 128 + r0;
  const int brw = wc * 64 + r0;

#define RD_A(Arr, slot, mq)                                                        \
  do {                                                                             \
    _Pragma("unroll")                                                              \
    for (int m = 0; m < 4; ++m)                                                    \
      Arr[m] = *(const s16x8*)&lds[slot][0][(arow + (mq) * 64 + m * 16) * 32 + cswz]; \
  } while (0)
#define RD_B(Arr, slot)                                                            \
  do {                                                                             \
    _Pragma("unroll")                                                              \
    for (int n = 0; n < 4; ++n)                                                    \
      Arr[n] = *(const s16x8*)&lds[slot][1][(brw + n * 16) * 32 + cswz];           \
  } while (0)
#define MM(mq, Aarr, Barr)                                                         \
  do {                                                                             \
    _Pragma("unroll")                                                              \
    for (int m = 0; m < 4; ++m) {                                                  \
      _Pragma("unroll")                                                            \
      for (int n = 0; n < 4; ++n)                                                  \
        acc[(mq) * 4 + m][n] = __builtin_amdgcn_mfma_f32_16x16x32_bf16(            \
            Aarr[m], Barr[n], acc[(mq) * 4 + m][n], 0, 0, 0);                      \
    }                                                                              \
  } while (0)
#define SBAR __builtin_amdgcn_sched_barrier(0)

  s16x8 AF0[4], AF1[4], BF0[4], BF1[4];

  // prologue: stage tiles 0,1,2 (12 loads); drain tile 0 (leave 8); preload frags
  STGA(0, 0); STGB(0, 0);
  STGA(1, 1); STGB(1, 1);
  STGA(2, 2); STGB(2, 2);
  asm volatile("s_waitcnt vmcnt(8)" ::: "memory");
  __builtin_amdgcn_s_barrier();
  RD_A(AF0, 0, 0);
  RD_B(BF0, 0);

  for (int kt = 0; kt < NT; kt += 2) {
    const int s0 = kt & 3, s1 = (kt + 1) & 3, s2 = (kt + 2) & 3, s3 = (kt + 3) & 3;
    // ---- P0 (tile kt, m0-3): stage A(kt+3); prefetch AF1; MFMA ----
    if (kt + 3 < NT) STGA(s3, kt + 3);
    RD_A(AF1, s0, 1);
    SBAR;
    __builtin_amdgcn_s_setprio(1);
    MM(0, AF0, BF0);
    __builtin_amdgcn_s_setprio(0);
    SBAR;
    // gate: tile kt+1 fully in LDS
    if (kt < NT - 2) asm volatile("s_waitcnt vmcnt(6)" ::: "memory");
    else             asm volatile("s_waitcnt vmcnt(0)" ::: "memory");
    __builtin_amdgcn_s_barrier();
    SBAR;
    // ---- P1 (tile kt, m4-7): stage B(kt+3); prefetch tile kt+1 frags ----
    if (kt + 3 < NT) STGB(s3, kt + 3);
    RD_A(AF0, s1, 0);
    RD_B(BF1, s1);
    SBAR;
    __builtin_amdgcn_s_setprio(1);
    MM(1, AF1, BF0);
    __builtin_amdgcn_s_setprio(0);
    SBAR;
    __builtin_amdgcn_s_barrier();
    SBAR;
    // ---- P2 (tile kt+1, m0-3): stage A(kt+4) into s0; prefetch AF1 ----
    if (kt + 4 < NT) STGA(s0, kt + 4);
    RD_A(AF1, s1, 1);
    SBAR;
    __builtin_amdgcn_s_setprio(1);
    MM(0, AF0, BF1);
    __builtin_amdgcn_s_setprio(0);
    SBAR;
    // gate: tile kt+2 fully in LDS
    if (kt < NT - 4)       asm volatile("s_waitcnt vmcnt(6)" ::: "memory");
    else if (kt == NT - 4) asm volatile("s_waitcnt vmcnt(4)" ::: "memory");
    else                   asm volatile("s_waitcnt vmcnt(0)" ::: "memory");
    __builtin_amdgcn_s_barrier();
    SBAR;
    // ---- P3 (tile kt+1, m4-7): stage B(kt+4); prefetch tile kt+2 frags ----
    if (kt + 4 < NT) STGB(s0, kt + 4);
    if (kt + 2 < NT) {
      RD_A(AF0, s2, 0);
      RD_B(BF0, s2);
    }
    SBAR;
    __builtin_amdgcn_s_setprio(1);
    MM(1, AF1, BF1);
    __builtin_amdgcn_s_setprio(0);
    SBAR;
    __builtin_amdgcn_s_barrier();
    SBAR;
  }
#undef SBAR
#undef MM
#undef RD_B
#undef RD_A
#undef STGB
#undef STGA

  const int g4 = g * 4;
#pragma unroll
  for (int m = 0; m < 8; ++m) {
#pragma unroll
    for (int n = 0; n < 4; ++n) {
      f32x4 v = acc[m][n];
      long col = bcol + wc * 64 + n * 16 + r0;
#pragma unroll
      for (int r = 0; r < 4; ++r) {
        long row = brow + wr * 128 + m * 16 + g4 + r;
        float val = v[r];
        if (EPI == 1) val += bias[col];
        if (EPI == 2) {
          long addr = ((col >> 9) << 21) + (row << 9) + (col & 511);
          C[addr] = f2bf(val);
        } else {
          C[row * (long)N + col] = f2bf(val);
        }
      }
    }
  }
}

// ---------------- fused attention ----------------
// grid: 1024 = B(16) * NH(16) * 4 q-tiles ; block: 512 (8 waves x 16 q-rows)
__global__ __launch_bounds__(512, 2) void attn_kernel(const unsigned short* __restrict__ Q,
                                                      const unsigned short* __restrict__ K,
                                                      const unsigned short* __restrict__ V,
                                                      const unsigned short* __restrict__ EP,
                                                      float* __restrict__ out) {
  __shared__ unsigned short lds[256 * 136]; // also used as [128][264]
  const int t = threadIdx.x;
  const int lane = t & 63;
  const int w = t >> 6;
  const int bid = blockIdx.x;
  const int qt = bid & 3;
  const int h = (bid >> 2) & 15;
  const int b = bid >> 6;
  const int r0 = lane & 15;
  const int g = lane >> 4;

  const int qrow = qt * 128 + w * 16;

  s16x8 qf[8];
  {
    const unsigned short* qp = Q + ((size_t)(b * 512 + qrow + r0)) * 4096 + h * 256 + g * 8;
#pragma unroll
    for (int s = 0; s < 8; ++s) qf[s] = *(const s16x8*)(qp + s * 32);
  }

  f32x4 st[32];
#pragma unroll
  for (int f = 0; f < 32; ++f) st[f] = f32x4{0.f, 0.f, 0.f, 0.f};

#pragma unroll
  for (int kc = 0; kc < 4; ++kc) {
    {
      const unsigned short* kp = K + ((size_t)(b * 512 + kc * 128)) * 4096 + h * 256;
#pragma unroll
      for (int u = 0; u < 8; ++u) {
        int fidx = u * 4096 + t * 8;
        int row = fidx >> 8, c = fidx & 255;
        u16x8 v = *(const u16x8*)(kp + (size_t)row * 4096 + c);
        *(u16x8*)&lds[row * 264 + c] = v;
      }
    }
    __syncthreads();
#pragma unroll
    for (int mf = 0; mf < 8; ++mf) {
      const unsigned short* lk = &lds[(mf * 16 + r0) * 264 + g * 8];
#pragma unroll
      for (int s = 0; s < 8; ++s) {
        s16x8 af = *(const s16x8*)(lk + s * 32);
        st[kc * 8 + mf] = __builtin_amdgcn_mfma_f32_16x16x32_bf16(af, qf[s], st[kc * 8 + mf], 0, 0, 0);
      }
    }
    __syncthreads();
  }

  {
    const unsigned short* ep = EP + ((size_t)(b * 512 + qrow + r0)) * 8192 + h * 512 + g * 4;
#pragma unroll
    for (int f = 0; f < 32; ++f) {
      u16x4 e = *(const u16x4*)(ep + f * 16);
#pragma unroll
      for (int r = 0; r < 4; ++r)
        st[f][r] = st[f][r] * 0.0625f + bf2f(e[r]);
    }
  }

  float mx = -1e30f;
#pragma unroll
  for (int f = 0; f < 32; ++f)
    mx = fmaxf(mx, fmaxf(fmaxf(st[f][0], st[f][1]), fmaxf(st[f][2], st[f][3])));
  mx = fmaxf(mx, __shfl_xor(mx, 16, 64));
  mx = fmaxf(mx, __shfl_xor(mx, 32, 64));
  float sum = 0.f;
#pragma unroll
  for (int f = 0; f < 32; ++f) {
#pragma unroll
    for (int r = 0; r < 4; ++r) {
      float e = __expf(st[f][r] - mx);
      st[f][r] = e;
      sum += e;
    }
  }
  sum += __shfl_xor(sum, 16, 64);
  sum += __shfl_xor(sum, 32, 64);
  const float rinv = 1.0f / sum;

  s16x8 pb[16];
#pragma unroll
  for (int p = 0; p < 16; ++p) {
    s16x8 v;
#pragma unroll
    for (int j = 0; j < 4; ++j) {
      v[j] = (short)f2bf(st[2 * p][j] * rinv);
      v[j + 4] = (short)f2bf(st[2 * p + 1][j] * rinv);
    }
    pb[p] = v;
  }

  f32x4 acc2[16];
#pragma unroll
  for (int d = 0; d < 16; ++d) acc2[d] = f32x4{0.f, 0.f, 0.f, 0.f};

#pragma unroll
  for (int kc = 0; kc < 4; ++kc) {
    {
      const unsigned short* vp = V + ((size_t)(b * 16 + h)) * 131072 + kc * 128;
#pragma unroll
      for (int u = 0; u < 8; ++u) {
        int fidx = u * 4096 + t * 8;
        int row = fidx >> 7, c = fidx & 127;
        u16x8 vv = *(const u16x8*)(vp + (size_t)row * 512 + c);
        *(u16x8*)&lds[row * 136 + c] = vv;
      }
    }
    __syncthreads();
#pragma unroll
    for (int d = 0; d < 16; ++d) {
      const unsigned short* lv = &lds[(d * 16 + r0) * 136 + g * 4];
#pragma unroll
      for (int p = 0; p < 4; ++p) {
        s16x4 a0 = *(const s16x4*)(lv + p * 32);
        s16x4 a1 = *(const s16x4*)(lv + p * 32 + 16);
        s16x8 av;
        av[0] = a0[0]; av[1] = a0[1]; av[2] = a0[2]; av[3] = a0[3];
        av[4] = a1[0]; av[5] = a1[1]; av[6] = a1[2]; av[7] = a1[3];
        acc2[d] = __builtin_amdgcn_mfma_f32_16x16x32_bf16(av, pb[kc * 4 + p], acc2[d], 0, 0, 0);
      }
    }
    __syncthreads();
  }

  {
    float* op = out + ((size_t)(b * 512 + qrow + r0)) * 4096 + h * 256 + g * 4;
#pragma unroll
    for (int d = 0; d < 16; ++d)
      *(fv4*)(op + d * 16) = acc2[d];
  }
}

// ---------------- host launch ----------------
extern "C" void kernel_launch(void* const* d_in, const int* in_sizes, int n_in,
                              void* d_out, int out_size, void* d_ws, size_t ws_size,
                              hipStream_t stream) {
  const float* x   = (const float*)d_in[0];
  const float* aug = (const float*)d_in[1];
  const float* wq  = (const float*)d_in[2];
  const float* wk  = (const float*)d_in[3];
  const float* wv  = (const float*)d_in[4];
  const float* wp  = (const float*)d_in[5];
  const float* bp  = (const float*)d_in[6];
  float* out = (float*)d_out;

  const size_t OFF_XA = 0;                       // 64 MiB: x_bf, later aug_bf
  const size_t OFF_WQ = 67108864;                // 32 MiB
  const size_t OFF_WK = OFF_WQ + 33554432;       // 32 MiB
  const size_t OFF_WV = OFF_WK + 33554432;       // 32 MiB (wp_bf overlays WQ+WK)
  const size_t OFF_Q  = OFF_WQ + 100663296;      // 64 MiB
  const size_t OFF_K  = OFF_Q + 67108864;        // 64 MiB
  const size_t OFF_VT = OFF_K + 67108864;        // 64 MiB
  const size_t OFF_EP = OFF_VT + 67108864;       // 128 MiB
  const size_t NEED   = OFF_EP + 134217728;      // 480 MiB total
  if (ws_size < NEED) return;

  char* ws = (char*)d_ws;
  unsigned short* x_bf   = (unsigned short*)(ws + OFF_XA);
  unsigned short* aug_bf = (unsigned short*)(ws + OFF_XA);
  unsigned short* wq_bf  = (unsigned short*)(ws + OFF_WQ);
  unsigned short* wk_bf  = (unsigned short*)(ws + OFF_WK);
  unsigned short* wv_bf  = (unsigned short*)(ws + OFF_WV);
  unsigned short* wp_bf  = (unsigned short*)(ws + OFF_WQ);
  unsigned short* q_bf   = (unsigned short*)(ws + OFF_Q);
  unsigned short* k_bf   = (unsigned short*)(ws + OFF_K);
  unsigned short* vt_bf  = (unsigned short*)(ws + OFF_VT);
  unsigned short* ep_bf  = (unsigned short*)(ws + OFF_EP);

  // phase A: convert x + QKV weights
  cvt_kernel<<<2048, 256, 0, stream>>>(x, x_bf, 33554432 / 4);
  cvt_kernel<<<2048, 256, 0, stream>>>(wq, wq_bf, 16777216 / 4);
  cvt_kernel<<<2048, 256, 0, stream>>>(wk, wk_bf, 16777216 / 4);
  cvt_kernel<<<2048, 256, 0, stream>>>(wv, wv_bf, 16777216 / 4);

  // Q = x @ Wq^T ; K = x @ Wk^T   (M=8192, N=4096) grid 32x16=512
  gemm256<0><<<512, 512, 0, stream>>>(x_bf, wq_bf, q_bf, nullptr, 4096, 4096, 4);
  gemm256<0><<<512, 512, 0, stream>>>(x_bf, wk_bf, k_bf, nullptr, 4096, 4096, 4);
  // Vt = Wv @ x^T  (M=4096, N=8192) grid 16x32=512
  gemm256<2><<<512, 512, 0, stream>>>(wv_bf, x_bf, vt_bf, nullptr, 8192, 4096, 5);

  // phase B: x_bf dead -> reuse for aug; wq/wk dead -> reuse for wp
  cvt_kernel<<<2048, 256, 0, stream>>>(aug, aug_bf, 33554432 / 4);
  cvt_kernel<<<2048, 256, 0, stream>>>(wp, wp_bf, 33554432 / 4);
  // EP = Aug @ Wp^T + bp  (M=8192, N=8192) grid 32x32=1024
  gemm256<1><<<1024, 512, 0, stream>>>(aug_bf, wp_bf, ep_bf, bp, 8192, 4096, 5);

  // fused attention
  attn_kernel<<<1024, 512, 0, stream>>>(q_bf, k_bf, vt_bf, ep_bf, out);
}

// Round 6
// 1741.614 us; speedup vs baseline: 48.2472x; 1.0104x over previous
//
#include <hip/hip_runtime.h>
#include <hip/hip_bf16.h>

typedef __attribute__((ext_vector_type(4))) float f32x4;
typedef __attribute__((ext_vector_type(8))) short s16x8;
typedef __attribute__((ext_vector_type(4))) short s16x4;
typedef __attribute__((ext_vector_type(8))) unsigned short u16x8;
typedef __attribute__((ext_vector_type(4))) unsigned short u16x4;
typedef __attribute__((ext_vector_type(4))) float fv4;

#define DEV static __device__ __forceinline__

DEV unsigned short f2bf(float f) {
  union { float f; unsigned u; } v; v.f = f;
  return (unsigned short)((v.u + 0x7fffu + ((v.u >> 16) & 1u)) >> 16);
}
DEV float bf2f(unsigned short u) {
  union { unsigned u; float f; } v; v.u = ((unsigned)u) << 16; return v.f;
}

typedef const __attribute__((address_space(1))) void* gas_t;
typedef __attribute__((address_space(3))) void* las_t;
DEV void load_lds16(const void* g, void* l) {
  __builtin_amdgcn_global_load_lds((gas_t)g, (las_t)l, 16, 0, 0);
}

// ---------------- fp32 -> bf16 convert ----------------
__global__ __launch_bounds__(256) void cvt_kernel(const float* __restrict__ in,
                                                  unsigned short* __restrict__ out,
                                                  int n4) {
  int i = blockIdx.x * 256 + threadIdx.x;
  int stride = gridDim.x * 256;
  for (; i < n4; i += stride) {
    fv4 v = *(const fv4*)(in + (size_t)i * 4);
    u16x4 o;
    o[0] = f2bf(v[0]); o[1] = f2bf(v[1]); o[2] = f2bf(v[2]); o[3] = f2bf(v[3]);
    *(u16x4*)(out + (size_t)i * 4) = o;
  }
}

// ------- 256x256 BT GEMM, BK=32, ring-4 LDS, frag-pipelined phases ---------
// C[m,n] = sum_k A[m,k]*B[n,k].  M,N mult of 256, K mult of 64 (NT even).
// Kernel body identical to R5 (verified: conflicts=0, VGPR 112, no spill).
// BLOCK MAPPING (R6 change): round-synchronized L3-friendly order.
//   round = 256 blocks; within a round all blocks share a byg-wide by band;
//   bid%8 (XCD, HW round-robin) picks by within the band -> each XCD's
//   2 MB A-panel stays in its private L2 for the whole bx sweep, and all
//   XCDs stream the SAME B panels concurrently (L3-resident, fetched ~once).
//   Old chunked swizzle desynchronized by-bands: 8 disjoint B streams,
//   1.28 GB HBM fetch for 134 MB of input = the 44%-MfmaUtil wall.
//   by = (bid>>(bxsh+bygsh))<<bygsh | (bid & (byg-1)); bx = (bid>>bygsh)&(nbx-1)
// EPI: 0 = bf16 out (ldc=N), 1 = +bias[n] bf16, 2 = Vt mapping
//   addr = (n>>9)*2^21 + m*512 + (n&511)
template<int EPI>
__global__ __launch_bounds__(512, 2) void gemm256(const unsigned short* __restrict__ A,
                                                  const unsigned short* __restrict__ B,
                                                  unsigned short* __restrict__ C,
                                                  const float* __restrict__ bias,
                                                  int N, int K, int bxsh, int bygsh) {
  __shared__ unsigned short lds[4][2][8192]; // [slot][A/B][256*32] = 128 KiB
  const int t = threadIdx.x;
  const int lane = t & 63;
  const int w = t >> 6;
  const int wr = w >> 2;   // 0..1
  const int wc = w & 3;    // 0..3
  const int r0 = lane & 15;
  const int g = lane >> 4; // 0..3

  const int bid = blockIdx.x;
  const int byg = 1 << bygsh;
  const int by = ((bid >> (bxsh + bygsh)) << bygsh) + (bid & (byg - 1));
  const int bx = (bid >> bygsh) & ((1 << bxsh) - 1);
  const long brow = (long)by * 256;
  const long bcol = (long)bx * 256;

  // staging: thread t -> 16B at LDS linear [t*8] and [4096+t*8]
  // dest row = t>>2 (0..127), chunk t&3; source chunk pre-swizzled by (t>>3)&3
  const int srow = t >> 2;
  const int scol = ((t & 3) ^ ((t >> 3) & 3)) * 8;
  const unsigned short* As = A + (brow + srow) * (long)K + scol;
  const unsigned short* Bs = B + (bcol + srow) * (long)K + scol;
  const int dst = t * 8;

#define STGA(slot, kt)                                                   \
  do {                                                                   \
    const long c0_ = (long)(kt) << 5;                                    \
    load_lds16(As + c0_,                 &lds[slot][0][dst]);            \
    load_lds16(As + 128 * (long)K + c0_, &lds[slot][0][4096 + dst]);     \
  } while (0)
#define STGB(slot, kt)                                                   \
  do {                                                                   \
    const long c0_ = (long)(kt) << 5;                                    \
    load_lds16(Bs + c0_,                 &lds[slot][1][dst]);            \
    load_lds16(Bs + 128 * (long)K + c0_, &lds[slot][1][4096 + dst]);     \
  } while (0)

  f32x4 acc[8][4] = {};
  const int NT = K >> 5; // even

  // swizzled k-chunk: (row>>1)&3 == (r0>>1)&3 for all frag rows
  const int cswz = (g ^ ((r0 >> 1) & 3)) * 8;
  const int arow = wr * 128 + r0;
  const int brw = wc * 64 + r0;

#define RD_A(Arr, slot, mq)                                                        \
  do {                                                                             \
    _Pragma("unroll")                                                              \
    for (int m = 0; m < 4; ++m)                                                    \
      Arr[m] = *(const s16x8*)&lds[slot][0][(arow + (mq) * 64 + m * 16) * 32 + cswz]; \
  } while (0)
#define RD_B(Arr, slot)                                                            \
  do {                                                                             \
    _Pragma("unroll")                                                              \
    for (int n = 0; n < 4; ++n)                                                    \
      Arr[n] = *(const s16x8*)&lds[slot][1][(brw + n * 16) * 32 + cswz];           \
  } while (0)
#define MM(mq, Aarr, Barr)                                                         \
  do {                                                                             \
    _Pragma("unroll")                                                              \
    for (int m = 0; m < 4; ++m) {                                                  \
      _Pragma("unroll")                                                            \
      for (int n = 0; n < 4; ++n)                                                  \
        acc[(mq) * 4 + m][n] = __builtin_amdgcn_mfma_f32_16x16x32_bf16(            \
            Aarr[m], Barr[n], acc[(mq) * 4 + m][n], 0, 0, 0);                      \
    }                                                                              \
  } while (0)
#define SBAR __builtin_amdgcn_sched_barrier(0)

  s16x8 AF0[4], AF1[4], BF0[4], BF1[4];

  // prologue: stage tiles 0,1,2 (12 loads); drain tile 0 (leave 8); preload frags
  STGA(0, 0); STGB(0, 0);
  STGA(1, 1); STGB(1, 1);
  STGA(2, 2); STGB(2, 2);
  asm volatile("s_waitcnt vmcnt(8)" ::: "memory");
  __builtin_amdgcn_s_barrier();
  RD_A(AF0, 0, 0);
  RD_B(BF0, 0);

  for (int kt = 0; kt < NT; kt += 2) {
    const int s0 = kt & 3, s1 = (kt + 1) & 3, s2 = (kt + 2) & 3, s3 = (kt + 3) & 3;
    // ---- P0 (tile kt, m0-3): stage A(kt+3); prefetch AF1; MFMA ----
    if (kt + 3 < NT) STGA(s3, kt + 3);
    RD_A(AF1, s0, 1);
    SBAR;
    __builtin_amdgcn_s_setprio(1);
    MM(0, AF0, BF0);
    __builtin_amdgcn_s_setprio(0);
    SBAR;
    // gate: tile kt+1 fully in LDS
    if (kt < NT - 2) asm volatile("s_waitcnt vmcnt(6)" ::: "memory");
    else             asm volatile("s_waitcnt vmcnt(0)" ::: "memory");
    __builtin_amdgcn_s_barrier();
    SBAR;
    // ---- P1 (tile kt, m4-7): stage B(kt+3); prefetch tile kt+1 frags ----
    if (kt + 3 < NT) STGB(s3, kt + 3);
    RD_A(AF0, s1, 0);
    RD_B(BF1, s1);
    SBAR;
    __builtin_amdgcn_s_setprio(1);
    MM(1, AF1, BF0);
    __builtin_amdgcn_s_setprio(0);
    SBAR;
    __builtin_amdgcn_s_barrier();
    SBAR;
    // ---- P2 (tile kt+1, m0-3): stage A(kt+4) into s0; prefetch AF1 ----
    if (kt + 4 < NT) STGA(s0, kt + 4);
    RD_A(AF1, s1, 1);
    SBAR;
    __builtin_amdgcn_s_setprio(1);
    MM(0, AF0, BF1);
    __builtin_amdgcn_s_setprio(0);
    SBAR;
    // gate: tile kt+2 fully in LDS
    if (kt < NT - 4)       asm volatile("s_waitcnt vmcnt(6)" ::: "memory");
    else if (kt == NT - 4) asm volatile("s_waitcnt vmcnt(4)" ::: "memory");
    else                   asm volatile("s_waitcnt vmcnt(0)" ::: "memory");
    __builtin_amdgcn_s_barrier();
    SBAR;
    // ---- P3 (tile kt+1, m4-7): stage B(kt+4); prefetch tile kt+2 frags ----
    if (kt + 4 < NT) STGB(s0, kt + 4);
    if (kt + 2 < NT) {
      RD_A(AF0, s2, 0);
      RD_B(BF0, s2);
    }
    SBAR;
    __builtin_amdgcn_s_setprio(1);
    MM(1, AF1, BF1);
    __builtin_amdgcn_s_setprio(0);
    SBAR;
    __builtin_amdgcn_s_barrier();
    SBAR;
  }
#undef SBAR
#undef MM
#undef RD_B
#undef RD_A
#undef STGB
#undef STGA

  const int g4 = g * 4;
#pragma unroll
  for (int m = 0; m < 8; ++m) {
#pragma unroll
    for (int n = 0; n < 4; ++n) {
      f32x4 v = acc[m][n];
      long col = bcol + wc * 64 + n * 16 + r0;
#pragma unroll
      for (int r = 0; r < 4; ++r) {
        long row = brow + wr * 128 + m * 16 + g4 + r;
        float val = v[r];
        if (EPI == 1) val += bias[col];
        if (EPI == 2) {
          long addr = ((col >> 9) << 21) + (row << 9) + (col & 511);
          C[addr] = f2bf(val);
        } else {
          C[row * (long)N + col] = f2bf(val);
        }
      }
    }
  }
}

// ---------------- fused attention ----------------
// grid: 1024 = B(16) * NH(16) * 4 q-tiles ; block: 512 (8 waves x 16 q-rows)
__global__ __launch_bounds__(512, 2) void attn_kernel(const unsigned short* __restrict__ Q,
                                                      const unsigned short* __restrict__ K,
                                                      const unsigned short* __restrict__ V,
                                                      const unsigned short* __restrict__ EP,
                                                      float* __restrict__ out) {
  __shared__ unsigned short lds[256 * 136]; // also used as [128][264]
  const int t = threadIdx.x;
  const int lane = t & 63;
  const int w = t >> 6;
  const int bid = blockIdx.x;
  const int qt = bid & 3;
  const int h = (bid >> 2) & 15;
  const int b = bid >> 6;
  const int r0 = lane & 15;
  const int g = lane >> 4;

  const int qrow = qt * 128 + w * 16;

  s16x8 qf[8];
  {
    const unsigned short* qp = Q + ((size_t)(b * 512 + qrow + r0)) * 4096 + h * 256 + g * 8;
#pragma unroll
    for (int s = 0; s < 8; ++s) qf[s] = *(const s16x8*)(qp + s * 32);
  }

  f32x4 st[32];
#pragma unroll
  for (int f = 0; f < 32; ++f) st[f] = f32x4{0.f, 0.f, 0.f, 0.f};

#pragma unroll
  for (int kc = 0; kc < 4; ++kc) {
    {
      const unsigned short* kp = K + ((size_t)(b * 512 + kc * 128)) * 4096 + h * 256;
#pragma unroll
      for (int u = 0; u < 8; ++u) {
        int fidx = u * 4096 + t * 8;
        int row = fidx >> 8, c = fidx & 255;
        u16x8 v = *(const u16x8*)(kp + (size_t)row * 4096 + c);
        *(u16x8*)&lds[row * 264 + c] = v;
      }
    }
    __syncthreads();
#pragma unroll
    for (int mf = 0; mf < 8; ++mf) {
      const unsigned short* lk = &lds[(mf * 16 + r0) * 264 + g * 8];
#pragma unroll
      for (int s = 0; s < 8; ++s) {
        s16x8 af = *(const s16x8*)(lk + s * 32);
        st[kc * 8 + mf] = __builtin_amdgcn_mfma_f32_16x16x32_bf16(af, qf[s], st[kc * 8 + mf], 0, 0, 0);
      }
    }
    __syncthreads();
  }

  {
    const unsigned short* ep = EP + ((size_t)(b * 512 + qrow + r0)) * 8192 + h * 512 + g * 4;
#pragma unroll
    for (int f = 0; f < 32; ++f) {
      u16x4 e = *(const u16x4*)(ep + f * 16);
#pragma unroll
      for (int r = 0; r < 4; ++r)
        st[f][r] = st[f][r] * 0.0625f + bf2f(e[r]);
    }
  }

  float mx = -1e30f;
#pragma unroll
  for (int f = 0; f < 32; ++f)
    mx = fmaxf(mx, fmaxf(fmaxf(st[f][0], st[f][1]), fmaxf(st[f][2], st[f][3])));
  mx = fmaxf(mx, __shfl_xor(mx, 16, 64));
  mx = fmaxf(mx, __shfl_xor(mx, 32, 64));
  float sum = 0.f;
#pragma unroll
  for (int f = 0; f < 32; ++f) {
#pragma unroll
    for (int r = 0; r < 4; ++r) {
      float e = __expf(st[f][r] - mx);
      st[f][r] = e;
      sum += e;
    }
  }
  sum += __shfl_xor(sum, 16, 64);
  sum += __shfl_xor(sum, 32, 64);
  const float rinv = 1.0f / sum;

  s16x8 pb[16];
#pragma unroll
  for (int p = 0; p < 16; ++p) {
    s16x8 v;
#pragma unroll
    for (int j = 0; j < 4; ++j) {
      v[j] = (short)f2bf(st[2 * p][j] * rinv);
      v[j + 4] = (short)f2bf(st[2 * p + 1][j] * rinv);
    }
    pb[p] = v;
  }

  f32x4 acc2[16];
#pragma unroll
  for (int d = 0; d < 16; ++d) acc2[d] = f32x4{0.f, 0.f, 0.f, 0.f};

#pragma unroll
  for (int kc = 0; kc < 4; ++kc) {
    {
      const unsigned short* vp = V + ((size_t)(b * 16 + h)) * 131072 + kc * 128;
#pragma unroll
      for (int u = 0; u < 8; ++u) {
        int fidx = u * 4096 + t * 8;
        int row = fidx >> 7, c = fidx & 127;
        u16x8 vv = *(const u16x8*)(vp + (size_t)row * 512 + c);
        *(u16x8*)&lds[row * 136 + c] = vv;
      }
    }
    __syncthreads();
#pragma unroll
    for (int d = 0; d < 16; ++d) {
      const unsigned short* lv = &lds[(d * 16 + r0) * 136 + g * 4];
#pragma unroll
      for (int p = 0; p < 4; ++p) {
        s16x4 a0 = *(const s16x4*)(lv + p * 32);
        s16x4 a1 = *(const s16x4*)(lv + p * 32 + 16);
        s16x8 av;
        av[0] = a0[0]; av[1] = a0[1]; av[2] = a0[2]; av[3] = a0[3];
        av[4] = a1[0]; av[5] = a1[1]; av[6] = a1[2]; av[7] = a1[3];
        acc2[d] = __builtin_amdgcn_mfma_f32_16x16x32_bf16(av, pb[kc * 4 + p], acc2[d], 0, 0, 0);
      }
    }
    __syncthreads();
  }

  {
    float* op = out + ((size_t)(b * 512 + qrow + r0)) * 4096 + h * 256 + g * 4;
#pragma unroll
    for (int d = 0; d < 16; ++d)
      *(fv4*)(op + d * 16) = acc2[d];
  }
}

// ---------------- host launch ----------------
extern "C" void kernel_launch(void* const* d_in, const int* in_sizes, int n_in,
                              void* d_out, int out_size, void* d_ws, size_t ws_size,
                              hipStream_t stream) {
  const float* x   = (const float*)d_in[0];
  const float* aug = (const float*)d_in[1];
  const float* wq  = (const float*)d_in[2];
  const float* wk  = (const float*)d_in[3];
  const float* wv  = (const float*)d_in[4];
  const float* wp  = (const float*)d_in[5];
  const float* bp  = (const float*)d_in[6];
  float* out = (float*)d_out;

  const size_t OFF_XA = 0;                       // 64 MiB: x_bf, later aug_bf
  const size_t OFF_WQ = 67108864;                // 32 MiB
  const size_t OFF_WK = OFF_WQ + 33554432;       // 32 MiB
  const size_t OFF_WV = OFF_WK + 33554432;       // 32 MiB (wp_bf overlays WQ+WK)
  const size_t OFF_Q  = OFF_WQ + 100663296;      // 64 MiB
  const size_t OFF_K  = OFF_Q + 67108864;        // 64 MiB
  const size_t OFF_VT = OFF_K + 67108864;        // 64 MiB
  const size_t OFF_EP = OFF_VT + 67108864;       // 128 MiB
  const size_t NEED   = OFF_EP + 134217728;      // 480 MiB total
  if (ws_size < NEED) return;

  char* ws = (char*)d_ws;
  unsigned short* x_bf   = (unsigned short*)(ws + OFF_XA);
  unsigned short* aug_bf = (unsigned short*)(ws + OFF_XA);
  unsigned short* wq_bf  = (unsigned short*)(ws + OFF_WQ);
  unsigned short* wk_bf  = (unsigned short*)(ws + OFF_WK);
  unsigned short* wv_bf  = (unsigned short*)(ws + OFF_WV);
  unsigned short* wp_bf  = (unsigned short*)(ws + OFF_WQ);
  unsigned short* q_bf   = (unsigned short*)(ws + OFF_Q);
  unsigned short* k_bf   = (unsigned short*)(ws + OFF_K);
  unsigned short* vt_bf  = (unsigned short*)(ws + OFF_VT);
  unsigned short* ep_bf  = (unsigned short*)(ws + OFF_EP);

  // phase A: convert x + QKV weights
  cvt_kernel<<<2048, 256, 0, stream>>>(x, x_bf, 33554432 / 4);
  cvt_kernel<<<2048, 256, 0, stream>>>(wq, wq_bf, 16777216 / 4);
  cvt_kernel<<<2048, 256, 0, stream>>>(wk, wk_bf, 16777216 / 4);
  cvt_kernel<<<2048, 256, 0, stream>>>(wv, wv_bf, 16777216 / 4);

  // Q = x @ Wq^T ; K = x @ Wk^T  (grid 32by x 16bx: bxsh=4, byg=16 -> bygsh=4)
  gemm256<0><<<512, 512, 0, stream>>>(x_bf, wq_bf, q_bf, nullptr, 4096, 4096, 4, 4);
  gemm256<0><<<512, 512, 0, stream>>>(x_bf, wk_bf, k_bf, nullptr, 4096, 4096, 4, 4);
  // Vt = Wv @ x^T  (grid 16by x 32bx: bxsh=5, byg=8 -> bygsh=3)
  gemm256<2><<<512, 512, 0, stream>>>(wv_bf, x_bf, vt_bf, nullptr, 8192, 4096, 5, 3);

  // phase B: x_bf dead -> reuse for aug; wq/wk dead -> reuse for wp
  cvt_kernel<<<2048, 256, 0, stream>>>(aug, aug_bf, 33554432 / 4);
  cvt_kernel<<<2048, 256, 0, stream>>>(wp, wp_bf, 33554432 / 4);
  // EP = Aug @ Wp^T + bp  (grid 32by x 32bx: bxsh=5, byg=8 -> bygsh=3)
  gemm256<1><<<1024, 512, 0, stream>>>(aug_bf, wp_bf, ep_bf, bp, 8192, 4096, 5, 3);

  // fused attention
  attn_kernel<<<1024, 512, 0, stream>>>(q_bf, k_bf, vt_bf, ep_bf, out);
}